// Round 10
// baseline (616.848 us; speedup 1.0000x reference)
//
#include <hip/hip_runtime.h>

#define N_NODES 20000
#define N_EDGES 640000
#define FDIM 64
#define NB 20
#define LN_EPS 1e-5f

typedef __attribute__((ext_vector_type(8))) short bf16x8;
typedef __attribute__((ext_vector_type(4))) float f32x4;

#define SEL_HI 0x07060302u
#define SEL_LO 0x05040100u
#define MFMA16 __builtin_amdgcn_mfma_f32_16x16x32_bf16

__device__ __forceinline__ float silu_f(float x) { return x / (1.0f + __expf(-x)); }

__device__ __forceinline__ float bcast_lane(float v, int lane) {
    return __int_as_float(__builtin_amdgcn_readlane(__float_as_int(v), lane));
}

__device__ __forceinline__ unsigned bf16_rn(float x) {
    unsigned u = __float_as_uint(x);
    return (u + 0x7FFFu + ((u >> 16) & 1u)) >> 16;
}

__device__ __forceinline__ unsigned pack_split(float x) {
    unsigned h = bf16_rn(x);
    unsigned lo = bf16_rn(x - __uint_as_float(h << 16));
    return (h << 16) | lo;
}

__device__ __forceinline__ void load_afrag(const unsigned* rowPtr, int kh, int q,
                                           bf16x8* ahi, bf16x8* alo) {
    const uint4 ra = *(const uint4*)(rowPtr + kh * 32 + q * 8);
    const uint4 rb = *(const uint4*)(rowPtr + kh * 32 + q * 8 + 4);
    union { unsigned u[4]; bf16x8 v; } H, L;
    H.u[0] = __builtin_amdgcn_perm(ra.y, ra.x, SEL_HI);
    H.u[1] = __builtin_amdgcn_perm(ra.w, ra.z, SEL_HI);
    H.u[2] = __builtin_amdgcn_perm(rb.y, rb.x, SEL_HI);
    H.u[3] = __builtin_amdgcn_perm(rb.w, rb.z, SEL_HI);
    L.u[0] = __builtin_amdgcn_perm(ra.y, ra.x, SEL_LO);
    L.u[1] = __builtin_amdgcn_perm(ra.w, ra.z, SEL_LO);
    L.u[2] = __builtin_amdgcn_perm(rb.y, rb.x, SEL_LO);
    L.u[3] = __builtin_amdgcn_perm(rb.w, rb.z, SEL_LO);
    *ahi = H.v;
    *alo = L.v;
}

__device__ __forceinline__ void mm3(const unsigned* Bhi, const unsigned* Blo,
                                    bf16x8 ahi, bf16x8 alo, f32x4* acc, int kh, int l) {
#pragma unroll
    for (int c = 0; c < 4; ++c) {
        bf16x8 bh = *(const bf16x8*)(Bhi + (kh * 4 + c) * 256 + l * 4);
        bf16x8 bl = *(const bf16x8*)(Blo + (kh * 4 + c) * 256 + l * 4);
        acc[c] = MFMA16(ahi, bh, acc[c], 0, 0, 0);
        acc[c] = MFMA16(ahi, bl, acc[c], 0, 0, 0);
        acc[c] = MFMA16(alo, bh, acc[c], 0, 0, 0);
    }
}

// ---------------- Kernel A: node MLP ----------------
__global__ __launch_bounds__(256) void node_mlp_kernel(
    const float* __restrict__ atom, const float* __restrict__ W1, const float* __restrict__ b1,
    const float* __restrict__ W2, const float* __restrict__ b2, float* __restrict__ mn)
{
    __shared__ float W1s[FDIM][FDIM];
    __shared__ float W2s[FDIM][FDIM];
    const int f = threadIdx.x, ty = threadIdx.y;
    const int tid = ty * 64 + f;
    for (int i = tid; i < FDIM * FDIM; i += 256) {
        ((float*)W1s)[i] = W1[i];
        ((float*)W2s)[i] = W2[i];
    }
    __syncthreads();
    const float bb1 = b1[f], bb2 = b2[f];
    const int nw = gridDim.x * 4;
    for (int n = blockIdx.x * 4 + ty; n < N_NODES; n += nw) {
        const float a = atom[n * FDIM + f];
        float h = bb1;
        for (int g = 0; g < FDIM; ++g) h += bcast_lane(a, g) * W1s[g][f];
        h = silu_f(h);
        float o = bb2;
        for (int g = 0; g < FDIM; ++g) o += bcast_lane(h, g) * W2s[g][f];
        mn[n * FDIM + f] = o;
    }
}

// ---------------- Kernel B: per-edge MFMA pipeline, drain-free scatter ----------------
// Key change vs R9: all 48 forceN[dst] gathers are hoisted into registers BEFORE the three
// MFMA phases; the scatter tail issues all 48 force atomics back-to-back with no dependent
// loads between them -> one vmcnt drain point per group instead of ~16.
__global__ __launch_bounds__(1024) void edge_kernel(
    const float* __restrict__ dist,   // [E,20]
    const float* __restrict__ dir,    // [E,3]
    const int* __restrict__ eidx,     // [2,E] int32
    const float* __restrict__ mn,     // [N,F]
    const float* __restrict__ We,     // [20,F]
    const float* __restrict__ Wq1a, const float* __restrict__ Wq1b,
    const float* __restrict__ Wq2a, const float* __restrict__ Wq2b,
    const float* __restrict__ forceN, // [N,3,F]
    float* __restrict__ atomAcc,      // [N,F]
    float* __restrict__ forceAcc)     // [N,3,F]
{
    __shared__ __align__(16) unsigned Bfr[16384];         // 64 KB weight frags
    __shared__ __align__(16) unsigned WeFr[2048];         // 8 KB We frags
    __shared__ __align__(16) unsigned Astg[16][16][76];   // per-wave staging

    const int l = threadIdx.x;
    const int ty = threadIdx.y;
    const int q = l >> 4, row = l & 15;

    for (int t = ty; t < 32; t += 16) {
        const int mm = t >> 3, kh = (t >> 2) & 1, c = t & 3;
        const float* W = (mm == 0) ? Wq1a : (mm == 1) ? Wq2a : (mm == 2) ? Wq1b : Wq2b;
        const int n = c * 16 + row;
        const int kb = kh * 32 + q * 8;
        unsigned* hiP = &Bfr[(((mm * 2 + 0) * 2 + kh) * 4 + c) * 256 + l * 4];
        unsigned* loP = &Bfr[(((mm * 2 + 1) * 2 + kh) * 4 + c) * 256 + l * 4];
#pragma unroll
        for (int i = 0; i < 4; ++i) {
            float w0 = W[(kb + 2 * i) * FDIM + n];
            float w1 = W[(kb + 2 * i + 1) * FDIM + n];
            unsigned h0 = bf16_rn(w0);
            unsigned l0 = bf16_rn(w0 - __uint_as_float(h0 << 16));
            unsigned h1 = bf16_rn(w1);
            unsigned l1 = bf16_rn(w1 - __uint_as_float(h1 << 16));
            hiP[i] = h0 | (h1 << 16);
            loP[i] = l0 | (l1 << 16);
        }
    }
    for (int c = ty; c < 4; c += 16) {
        const int n = c * 16 + row;
        unsigned* hiP = &WeFr[(0 * 4 + c) * 256 + l * 4];
        unsigned* loP = &WeFr[(1 * 4 + c) * 256 + l * 4];
#pragma unroll
        for (int i = 0; i < 4; ++i) {
            const int k0 = q * 8 + 2 * i, k1 = k0 + 1;
            float w0 = (k0 < NB) ? We[k0 * FDIM + n] : 0.0f;
            float w1 = (k1 < NB) ? We[k1 * FDIM + n] : 0.0f;
            unsigned h0 = bf16_rn(w0);
            unsigned l0 = bf16_rn(w0 - __uint_as_float(h0 << 16));
            unsigned h1 = bf16_rn(w1);
            unsigned l1 = bf16_rn(w1 - __uint_as_float(h1 << 16));
            hiP[i] = h0 | (h1 << 16);
            loP[i] = l0 | (l1 << 16);
        }
    }
    __syncthreads();

    const unsigned* B1aH = Bfr + 0 * 2048; const unsigned* B1aL = Bfr + 1 * 2048;
    const unsigned* B2aH = Bfr + 2 * 2048; const unsigned* B2aL = Bfr + 3 * 2048;
    const unsigned* B1bH = Bfr + 4 * 2048; const unsigned* B1bL = Bfr + 5 * 2048;
    const unsigned* B2bH = Bfr + 6 * 2048; const unsigned* B2bL = Bfr + 7 * 2048;
    const unsigned* WeH = WeFr;            const unsigned* WeL = WeFr + 1024;

    unsigned* stg = &Astg[ty][0][0];
    const unsigned* rowPtr = &Astg[ty][row][0];

    const int ngroups = N_EDGES / 16;
    const int stride = gridDim.x * 16;
    int grp = blockIdx.x * 16 + ty;

    // ---- prologue ----
    int e0 = grp * 16;
    int evA = (l < 32) ? eidx[(l < 16) ? (e0 + l) : (N_EDGES + e0 + (l - 16))] : 0;
    float dvA = (l < 48) ? dir[e0 * 3 + l] : 0.0f;
    float4 daA = {0.f, 0.f, 0.f, 0.f}, dbA = {0.f, 0.f, 0.f, 0.f};
    {
        const float* dp = dist + (size_t)(e0 + row) * NB + q * 8;
        if (q < 2)       { daA = *(const float4*)dp; dbA = *(const float4*)(dp + 4); }
        else if (q == 2) { daA = *(const float4*)dp; }
    }
    float mnS[16], mnD[16];
#pragma unroll
    for (int j = 0; j < 16; ++j) {
        const int src = __builtin_amdgcn_readlane(evA, j);
        const int dst = __builtin_amdgcn_readlane(evA, 16 + j);
        mnS[j] = mn[(size_t)src * FDIM + l];
        mnD[j] = mn[(size_t)dst * FDIM + l];
    }

    while (grp < ngroups) {
        e0 = grp * 16;
        const int grpN = grp + stride;
        const int e0n = (grpN < ngroups) ? grpN * 16 : 0;

        // next-group metadata loads
        const int evB = (l < 32) ? eidx[(l < 16) ? (e0n + l) : (N_EDGES + e0n + (l - 16))] : 0;
        const float dvB = (l < 48) ? dir[e0n * 3 + l] : 0.0f;

        // ---- me = dist16x20 @ We20x64 via MFMA ----
        unsigned s0 = pack_split(daA.x), s1 = pack_split(daA.y);
        unsigned s2 = pack_split(daA.z), s3 = pack_split(daA.w);
        unsigned s4 = pack_split(dbA.x), s5 = pack_split(dbA.y);
        unsigned s6 = pack_split(dbA.z), s7 = pack_split(dbA.w);
        union { unsigned u[4]; bf16x8 v; } AH, AL;
        AH.u[0] = __builtin_amdgcn_perm(s1, s0, SEL_HI);
        AH.u[1] = __builtin_amdgcn_perm(s3, s2, SEL_HI);
        AH.u[2] = __builtin_amdgcn_perm(s5, s4, SEL_HI);
        AH.u[3] = __builtin_amdgcn_perm(s7, s6, SEL_HI);
        AL.u[0] = __builtin_amdgcn_perm(s1, s0, SEL_LO);
        AL.u[1] = __builtin_amdgcn_perm(s3, s2, SEL_LO);
        AL.u[2] = __builtin_amdgcn_perm(s5, s4, SEL_LO);
        AL.u[3] = __builtin_amdgcn_perm(s7, s6, SEL_LO);

        f32x4 me4[4];
#pragma unroll
        for (int c = 0; c < 4; ++c) me4[c] = (f32x4){0.f, 0.f, 0.f, 0.f};
        mm3(WeH, WeL, AH.v, AL.v, me4, 0, l);
#pragma unroll
        for (int c = 0; c < 4; ++c)
#pragma unroll
            for (int r = 0; r < 4; ++r)
                stg[(q * 4 + r) * 76 + (row + 16 * c)] = __float_as_uint(me4[c][r]);

        // next-group dist loads
        float4 daB = {0.f, 0.f, 0.f, 0.f}, dbB = {0.f, 0.f, 0.f, 0.f};
        {
            const float* dpn = dist + (size_t)(e0n + row) * NB + q * 8;
            if (q < 2)       { daB = *(const float4*)dpn; dbB = *(const float4*)(dpn + 4); }
            else if (q == 2) { daB = *(const float4*)dpn; }
        }

        // ---- msg loop (prefetched mn; 16 atomAcc atomics) ----
#pragma unroll
        for (int j = 0; j < 16; ++j) {
            const int src = __builtin_amdgcn_readlane(evA, j);
            const float me = __uint_as_float(stg[j * 76 + l]);
            const float m = me * mnS[j] * mnD[j];
            atomicAdd(&atomAcc[(size_t)src * FDIM + l], m);
            stg[j * 76 + l] = pack_split(m);
        }

        // ---- next-group mn gathers (fly under MFMA phases) ----
#pragma unroll
        for (int j = 0; j < 16; ++j) {
            const int srcN = __builtin_amdgcn_readlane(evB, j);
            const int dstN = __builtin_amdgcn_readlane(evB, 16 + j);
            mnS[j] = mn[(size_t)srcN * FDIM + l];
            mnD[j] = mn[(size_t)dstN * FDIM + l];
        }

        // ---- hoist ALL forceN[dst] gathers into registers (land under MFMA phases) ----
        float fd0[4][4], fd1[4][4], fd2[4][4];
#pragma unroll
        for (int r = 0; r < 4; ++r) {
            const int eo = q * 4 + r;
            const int vd = __shfl(evA, 16 + eo);
            const float* fd = forceN + (size_t)vd * 3 * FDIM;
#pragma unroll
            for (int c = 0; c < 4; ++c) {
                const int n = row + 16 * c;
                fd0[r][c] = fd[0 * FDIM + n];
                fd1[r][c] = fd[1 * FDIM + n];
                fd2[r][c] = fd[2 * FDIM + n];
            }
        }

        // ---- h-phase: h1 = msg@Wq1a, h2 = msg@Wq2a ----
        f32x4 acc1[4], acc2[4];
#pragma unroll
        for (int c = 0; c < 4; ++c) {
            acc1[c] = (f32x4){0.f, 0.f, 0.f, 0.f};
            acc2[c] = (f32x4){0.f, 0.f, 0.f, 0.f};
        }
#pragma unroll
        for (int kh = 0; kh < 2; ++kh) {
            bf16x8 ahi, alo;
            load_afrag(rowPtr, kh, q, &ahi, &alo);
            mm3(B1aH, B1aL, ahi, alo, acc1, kh, l);
            mm3(B2aH, B2aL, ahi, alo, acc2, kh, l);
        }
#pragma unroll
        for (int c = 0; c < 4; ++c)
#pragma unroll
            for (int r = 0; r < 4; ++r) {
                acc1[c][r] = silu_f(acc1[c][r]);
                acc2[c][r] = silu_f(acc2[c][r]);
            }

        // ---- stage h1, e1 = h1@Wq1b ----
#pragma unroll
        for (int c = 0; c < 4; ++c)
#pragma unroll
            for (int r = 0; r < 4; ++r)
                stg[(q * 4 + r) * 76 + (row + 16 * c)] = pack_split(acc1[c][r]);
        f32x4 eacc1[4];
#pragma unroll
        for (int c = 0; c < 4; ++c) eacc1[c] = (f32x4){0.f, 0.f, 0.f, 0.f};
#pragma unroll
        for (int kh = 0; kh < 2; ++kh) {
            bf16x8 ahi, alo;
            load_afrag(rowPtr, kh, q, &ahi, &alo);
            mm3(B1bH, B1bL, ahi, alo, eacc1, kh, l);
        }

        // ---- stage h2, e2 = h2@Wq2b ----
#pragma unroll
        for (int c = 0; c < 4; ++c)
#pragma unroll
            for (int r = 0; r < 4; ++r)
                stg[(q * 4 + r) * 76 + (row + 16 * c)] = pack_split(acc2[c][r]);
        f32x4 eacc2[4];
#pragma unroll
        for (int c = 0; c < 4; ++c) eacc2[c] = (f32x4){0.f, 0.f, 0.f, 0.f};
#pragma unroll
        for (int kh = 0; kh < 2; ++kh) {
            bf16x8 ahi, alo;
            load_afrag(rowPtr, kh, q, &ahi, &alo);
            mm3(B2bH, B2bL, ahi, alo, eacc2, kh, l);
        }

        // ---- scatter tail: all-register computation, 48 atomics back-to-back, no loads ----
#pragma unroll
        for (int r = 0; r < 4; ++r) {
            const int eo = q * 4 + r;
            const int vs = __shfl(evA, eo);
            const float d0 = __shfl(dvA, eo * 3 + 0);
            const float d1 = __shfl(dvA, eo * 3 + 1);
            const float d2 = __shfl(dvA, eo * 3 + 2);
            float* fa = forceAcc + (size_t)vs * 3 * FDIM;
#pragma unroll
            for (int c = 0; c < 4; ++c) {
                const int n = row + 16 * c;
                const float a = eacc1[c][r];
                const float b = eacc2[c][r];
                atomicAdd(&fa[0 * FDIM + n], a * d0 + b * fd0[r][c]);
                atomicAdd(&fa[1 * FDIM + n], a * d1 + b * fd1[r][c]);
                atomicAdd(&fa[2 * FDIM + n], a * d2 + b * fd2[r][c]);
            }
        }

        // ---- rotate ----
        evA = evB;
        dvA = dvB;
        daA = daB;
        dbA = dbB;
        grp = grpN;
    }
}

// ---------------- Kernel C: finalize nodes ----------------
__global__ __launch_bounds__(256) void node_final_kernel(
    const float* __restrict__ Wu, const float* __restrict__ gamma, const float* __restrict__ beta,
    float* __restrict__ atomAcc, const float* __restrict__ forceOut)
{
    __shared__ float Wus[FDIM][FDIM];
    const int f = threadIdx.x, ty = threadIdx.y;
    const int tid = ty * 64 + f;
    for (int i = tid; i < FDIM * FDIM; i += 256) ((float*)Wus)[i] = Wu[i];
    __syncthreads();
    const float gg = gamma[f], bb = beta[f];
    const int nw = gridDim.x * 4;
    for (int n = blockIdx.x * 4 + ty; n < N_NODES; n += nw) {
        const float f0 = forceOut[((size_t)n * 3 + 0) * FDIM + f];
        const float f1 = forceOut[((size_t)n * 3 + 1) * FDIM + f];
        const float f2 = forceOut[((size_t)n * 3 + 2) * FDIM + f];
        float r0 = 0.0f, r1 = 0.0f, r2 = 0.0f;
#pragma unroll 8
        for (int g = 0; g < FDIM; ++g) {
            const float w = Wus[g][f];
            r0 += bcast_lane(f0, g) * w;
            r1 += bcast_lane(f1, g) * w;
            r2 += bcast_lane(f2, g) * w;
        }
        float a = atomAcc[n * FDIM + f] + (f0 * r0 + f1 * r1 + f2 * r2);
        float s = a;
#pragma unroll
        for (int off = 32; off >= 1; off >>= 1) s += __shfl_xor(s, off, 64);
        const float mu = s * (1.0f / 64.0f);
        const float d = a - mu;
        float v = d * d;
#pragma unroll
        for (int off = 32; off >= 1; off >>= 1) v += __shfl_xor(v, off, 64);
        v *= (1.0f / 64.0f);
        atomAcc[n * FDIM + f] = d * rsqrtf(v + LN_EPS) * gg + bb;
    }
}

extern "C" void kernel_launch(void* const* d_in, const int* in_sizes, int n_in,
                              void* d_out, int out_size, void* d_ws, size_t ws_size,
                              hipStream_t stream)
{
    const float* atom_node  = (const float*)d_in[0];
    const float* force_node = (const float*)d_in[1];
    const float* dir_edge   = (const float*)d_in[2];
    const float* dist_edge  = (const float*)d_in[3];
    const int*   edge_index = (const int*)d_in[4];
    const float* W1   = (const float*)d_in[5];
    const float* b1   = (const float*)d_in[6];
    const float* W2   = (const float*)d_in[7];
    const float* b2   = (const float*)d_in[8];
    const float* We   = (const float*)d_in[9];
    const float* Wq1a = (const float*)d_in[10];
    const float* Wq1b = (const float*)d_in[11];
    const float* Wq2a = (const float*)d_in[12];
    const float* Wq2b = (const float*)d_in[13];
    const float* Wu   = (const float*)d_in[14];
    const float* gamma = (const float*)d_in[15];
    const float* beta  = (const float*)d_in[16];

    float* atomOut  = (float*)d_out;
    float* forceOut = (float*)d_out + (size_t)N_NODES * FDIM;
    float* mn = (float*)d_ws;

    hipMemcpyAsync(atomOut, atom_node, (size_t)N_NODES * FDIM * sizeof(float),
                   hipMemcpyDeviceToDevice, stream);
    hipMemcpyAsync(forceOut, force_node, (size_t)N_NODES * 3 * FDIM * sizeof(float),
                   hipMemcpyDeviceToDevice, stream);

    dim3 blk4(64, 4);
    dim3 blk16(64, 16);
    node_mlp_kernel<<<512, blk4, 0, stream>>>(atom_node, W1, b1, W2, b2, mn);
    edge_kernel<<<256, blk16, 0, stream>>>(dist_edge, dir_edge, edge_index, mn, We,
                                           Wq1a, Wq1b, Wq2a, Wq2b, force_node,
                                           atomOut, forceOut);
    node_final_kernel<<<512, blk4, 0, stream>>>(Wu, gamma, beta, atomOut, forceOut);
}

// Round 11
// 595.482 us; speedup vs baseline: 1.0359x; 1.0359x over previous
//
#include <hip/hip_runtime.h>

#define N_NODES 20000
#define N_EDGES 640000
#define FDIM 64
#define NB 20
#define LN_EPS 1e-5f

typedef __attribute__((ext_vector_type(8))) short bf16x8;
typedef __attribute__((ext_vector_type(4))) float f32x4;

#define SEL_HI 0x07060302u
#define SEL_LO 0x05040100u
#define MFMA16 __builtin_amdgcn_mfma_f32_16x16x32_bf16

__device__ __forceinline__ float silu_f(float x) { return x / (1.0f + __expf(-x)); }

__device__ __forceinline__ float bcast_lane(float v, int lane) {
    return __int_as_float(__builtin_amdgcn_readlane(__float_as_int(v), lane));
}

__device__ __forceinline__ unsigned bf16_rn(float x) {
    unsigned u = __float_as_uint(x);
    return (u + 0x7FFFu + ((u >> 16) & 1u)) >> 16;
}

__device__ __forceinline__ unsigned pack_split(float x) {
    unsigned h = bf16_rn(x);
    unsigned lo = bf16_rn(x - __uint_as_float(h << 16));
    return (h << 16) | lo;
}

__device__ __forceinline__ void load_afrag(const unsigned* rowPtr, int kh, int q,
                                           bf16x8* ahi, bf16x8* alo) {
    const uint4 ra = *(const uint4*)(rowPtr + kh * 32 + q * 8);
    const uint4 rb = *(const uint4*)(rowPtr + kh * 32 + q * 8 + 4);
    union { unsigned u[4]; bf16x8 v; } H, L;
    H.u[0] = __builtin_amdgcn_perm(ra.y, ra.x, SEL_HI);
    H.u[1] = __builtin_amdgcn_perm(ra.w, ra.z, SEL_HI);
    H.u[2] = __builtin_amdgcn_perm(rb.y, rb.x, SEL_HI);
    H.u[3] = __builtin_amdgcn_perm(rb.w, rb.z, SEL_HI);
    L.u[0] = __builtin_amdgcn_perm(ra.y, ra.x, SEL_LO);
    L.u[1] = __builtin_amdgcn_perm(ra.w, ra.z, SEL_LO);
    L.u[2] = __builtin_amdgcn_perm(rb.y, rb.x, SEL_LO);
    L.u[3] = __builtin_amdgcn_perm(rb.w, rb.z, SEL_LO);
    *ahi = H.v;
    *alo = L.v;
}

__device__ __forceinline__ void mm3(const unsigned* Bhi, const unsigned* Blo,
                                    bf16x8 ahi, bf16x8 alo, f32x4* acc, int kh, int l) {
#pragma unroll
    for (int c = 0; c < 4; ++c) {
        bf16x8 bh = *(const bf16x8*)(Bhi + (kh * 4 + c) * 256 + l * 4);
        bf16x8 bl = *(const bf16x8*)(Blo + (kh * 4 + c) * 256 + l * 4);
        acc[c] = MFMA16(ahi, bh, acc[c], 0, 0, 0);
        acc[c] = MFMA16(ahi, bl, acc[c], 0, 0, 0);
        acc[c] = MFMA16(alo, bh, acc[c], 0, 0, 0);
    }
}

// ---------------- Kernel A: node MLP ----------------
__global__ __launch_bounds__(256) void node_mlp_kernel(
    const float* __restrict__ atom, const float* __restrict__ W1, const float* __restrict__ b1,
    const float* __restrict__ W2, const float* __restrict__ b2, float* __restrict__ mn)
{
    __shared__ float W1s[FDIM][FDIM];
    __shared__ float W2s[FDIM][FDIM];
    const int f = threadIdx.x, ty = threadIdx.y;
    const int tid = ty * 64 + f;
    for (int i = tid; i < FDIM * FDIM; i += 256) {
        ((float*)W1s)[i] = W1[i];
        ((float*)W2s)[i] = W2[i];
    }
    __syncthreads();
    const float bb1 = b1[f], bb2 = b2[f];
    const int nw = gridDim.x * 4;
    for (int n = blockIdx.x * 4 + ty; n < N_NODES; n += nw) {
        const float a = atom[n * FDIM + f];
        float h = bb1;
        for (int g = 0; g < FDIM; ++g) h += bcast_lane(a, g) * W1s[g][f];
        h = silu_f(h);
        float o = bb2;
        for (int g = 0; g < FDIM; ++g) o += bcast_lane(h, g) * W2s[g][f];
        mn[n * FDIM + f] = o;
    }
}

// ---------------- Kernel B: per-edge MFMA pipeline ----------------
// R9 structure; __launch_bounds__(1024, 1) so the register allocator can use up to
// ~128+ VGPRs instead of spilling the prefetch arrays to scratch (R9/R10 ran at 64
// VGPR with 200+MB of scratch traffic — the pipelining never actually happened).
// LDS caps occupancy at 1 block (16 waves)/CU regardless, so no occupancy loss.
__global__ __launch_bounds__(1024, 1) void edge_kernel(
    const float* __restrict__ dist,   // [E,20]
    const float* __restrict__ dir,    // [E,3]
    const int* __restrict__ eidx,     // [2,E] int32
    const float* __restrict__ mn,     // [N,F]
    const float* __restrict__ We,     // [20,F]
    const float* __restrict__ Wq1a, const float* __restrict__ Wq1b,
    const float* __restrict__ Wq2a, const float* __restrict__ Wq2b,
    const float* __restrict__ forceN, // [N,3,F]
    float* __restrict__ atomAcc,      // [N,F]
    float* __restrict__ forceAcc)     // [N,3,F]
{
    __shared__ __align__(16) unsigned Bfr[16384];         // 64 KB weight frags
    __shared__ __align__(16) unsigned WeFr[2048];         // 8 KB We frags
    __shared__ __align__(16) unsigned Astg[16][16][76];   // per-wave staging

    const int l = threadIdx.x;
    const int ty = threadIdx.y;
    const int q = l >> 4, row = l & 15;

    for (int t = ty; t < 32; t += 16) {
        const int mm = t >> 3, kh = (t >> 2) & 1, c = t & 3;
        const float* W = (mm == 0) ? Wq1a : (mm == 1) ? Wq2a : (mm == 2) ? Wq1b : Wq2b;
        const int n = c * 16 + row;
        const int kb = kh * 32 + q * 8;
        unsigned* hiP = &Bfr[(((mm * 2 + 0) * 2 + kh) * 4 + c) * 256 + l * 4];
        unsigned* loP = &Bfr[(((mm * 2 + 1) * 2 + kh) * 4 + c) * 256 + l * 4];
#pragma unroll
        for (int i = 0; i < 4; ++i) {
            float w0 = W[(kb + 2 * i) * FDIM + n];
            float w1 = W[(kb + 2 * i + 1) * FDIM + n];
            unsigned h0 = bf16_rn(w0);
            unsigned l0 = bf16_rn(w0 - __uint_as_float(h0 << 16));
            unsigned h1 = bf16_rn(w1);
            unsigned l1 = bf16_rn(w1 - __uint_as_float(h1 << 16));
            hiP[i] = h0 | (h1 << 16);
            loP[i] = l0 | (l1 << 16);
        }
    }
    for (int c = ty; c < 4; c += 16) {
        const int n = c * 16 + row;
        unsigned* hiP = &WeFr[(0 * 4 + c) * 256 + l * 4];
        unsigned* loP = &WeFr[(1 * 4 + c) * 256 + l * 4];
#pragma unroll
        for (int i = 0; i < 4; ++i) {
            const int k0 = q * 8 + 2 * i, k1 = k0 + 1;
            float w0 = (k0 < NB) ? We[k0 * FDIM + n] : 0.0f;
            float w1 = (k1 < NB) ? We[k1 * FDIM + n] : 0.0f;
            unsigned h0 = bf16_rn(w0);
            unsigned l0 = bf16_rn(w0 - __uint_as_float(h0 << 16));
            unsigned h1 = bf16_rn(w1);
            unsigned l1 = bf16_rn(w1 - __uint_as_float(h1 << 16));
            hiP[i] = h0 | (h1 << 16);
            loP[i] = l0 | (l1 << 16);
        }
    }
    __syncthreads();

    const unsigned* B1aH = Bfr + 0 * 2048; const unsigned* B1aL = Bfr + 1 * 2048;
    const unsigned* B2aH = Bfr + 2 * 2048; const unsigned* B2aL = Bfr + 3 * 2048;
    const unsigned* B1bH = Bfr + 4 * 2048; const unsigned* B1bL = Bfr + 5 * 2048;
    const unsigned* B2bH = Bfr + 6 * 2048; const unsigned* B2bL = Bfr + 7 * 2048;
    const unsigned* WeH = WeFr;            const unsigned* WeL = WeFr + 1024;

    unsigned* stg = &Astg[ty][0][0];
    const unsigned* rowPtr = &Astg[ty][row][0];

    const int ngroups = N_EDGES / 16;
    const int stride = gridDim.x * 16;
    int grp = blockIdx.x * 16 + ty;

    // ---- prologue ----
    int e0 = grp * 16;
    int evA = (l < 32) ? eidx[(l < 16) ? (e0 + l) : (N_EDGES + e0 + (l - 16))] : 0;
    float dvA = (l < 48) ? dir[e0 * 3 + l] : 0.0f;
    float4 daA = {0.f, 0.f, 0.f, 0.f}, dbA = {0.f, 0.f, 0.f, 0.f};
    {
        const float* dp = dist + (size_t)(e0 + row) * NB + q * 8;
        if (q < 2)       { daA = *(const float4*)dp; dbA = *(const float4*)(dp + 4); }
        else if (q == 2) { daA = *(const float4*)dp; }
    }
    float mnS[16], mnD[16];
#pragma unroll
    for (int j = 0; j < 16; ++j) {
        const int src = __builtin_amdgcn_readlane(evA, j);
        const int dst = __builtin_amdgcn_readlane(evA, 16 + j);
        mnS[j] = mn[(size_t)src * FDIM + l];
        mnD[j] = mn[(size_t)dst * FDIM + l];
    }

    while (grp < ngroups) {
        e0 = grp * 16;
        const int grpN = grp + stride;
        const int e0n = (grpN < ngroups) ? grpN * 16 : 0;

        // next-group metadata loads (fly under me-phase)
        const int evB = (l < 32) ? eidx[(l < 16) ? (e0n + l) : (N_EDGES + e0n + (l - 16))] : 0;
        const float dvB = (l < 48) ? dir[e0n * 3 + l] : 0.0f;

        // ---- me = dist16x20 @ We20x64 via MFMA ----
        unsigned s0 = pack_split(daA.x), s1 = pack_split(daA.y);
        unsigned s2 = pack_split(daA.z), s3 = pack_split(daA.w);
        unsigned s4 = pack_split(dbA.x), s5 = pack_split(dbA.y);
        unsigned s6 = pack_split(dbA.z), s7 = pack_split(dbA.w);
        union { unsigned u[4]; bf16x8 v; } AH, AL;
        AH.u[0] = __builtin_amdgcn_perm(s1, s0, SEL_HI);
        AH.u[1] = __builtin_amdgcn_perm(s3, s2, SEL_HI);
        AH.u[2] = __builtin_amdgcn_perm(s5, s4, SEL_HI);
        AH.u[3] = __builtin_amdgcn_perm(s7, s6, SEL_HI);
        AL.u[0] = __builtin_amdgcn_perm(s1, s0, SEL_LO);
        AL.u[1] = __builtin_amdgcn_perm(s3, s2, SEL_LO);
        AL.u[2] = __builtin_amdgcn_perm(s5, s4, SEL_LO);
        AL.u[3] = __builtin_amdgcn_perm(s7, s6, SEL_LO);

        f32x4 me4[4];
#pragma unroll
        for (int c = 0; c < 4; ++c) me4[c] = (f32x4){0.f, 0.f, 0.f, 0.f};
        mm3(WeH, WeL, AH.v, AL.v, me4, 0, l);
#pragma unroll
        for (int c = 0; c < 4; ++c)
#pragma unroll
            for (int r = 0; r < 4; ++r)
                stg[(q * 4 + r) * 76 + (row + 16 * c)] = __float_as_uint(me4[c][r]);

        // next-group dist loads (fly under msg + MFMA phases)
        float4 daB = {0.f, 0.f, 0.f, 0.f}, dbB = {0.f, 0.f, 0.f, 0.f};
        {
            const float* dpn = dist + (size_t)(e0n + row) * NB + q * 8;
            if (q < 2)       { daB = *(const float4*)dpn; dbB = *(const float4*)(dpn + 4); }
            else if (q == 2) { daB = *(const float4*)dpn; }
        }

        // ---- msg loop (prefetched mn; 16 atomAcc atomics) ----
#pragma unroll
        for (int j = 0; j < 16; ++j) {
            const int src = __builtin_amdgcn_readlane(evA, j);
            const float me = __uint_as_float(stg[j * 76 + l]);
            const float m = me * mnS[j] * mnD[j];
            atomicAdd(&atomAcc[(size_t)src * FDIM + l], m);
            stg[j * 76 + l] = pack_split(m);
        }

        // ---- next-group mn gathers (fly under MFMA phases) ----
#pragma unroll
        for (int j = 0; j < 16; ++j) {
            const int srcN = __builtin_amdgcn_readlane(evB, j);
            const int dstN = __builtin_amdgcn_readlane(evB, 16 + j);
            mnS[j] = mn[(size_t)srcN * FDIM + l];
            mnD[j] = mn[(size_t)dstN * FDIM + l];
        }

        // ---- h-phase: h1 = msg@Wq1a, h2 = msg@Wq2a ----
        f32x4 acc1[4], acc2[4];
#pragma unroll
        for (int c = 0; c < 4; ++c) {
            acc1[c] = (f32x4){0.f, 0.f, 0.f, 0.f};
            acc2[c] = (f32x4){0.f, 0.f, 0.f, 0.f};
        }
#pragma unroll
        for (int kh = 0; kh < 2; ++kh) {
            bf16x8 ahi, alo;
            load_afrag(rowPtr, kh, q, &ahi, &alo);
            mm3(B1aH, B1aL, ahi, alo, acc1, kh, l);
            mm3(B2aH, B2aL, ahi, alo, acc2, kh, l);
        }
#pragma unroll
        for (int c = 0; c < 4; ++c)
#pragma unroll
            for (int r = 0; r < 4; ++r) {
                acc1[c][r] = silu_f(acc1[c][r]);
                acc2[c][r] = silu_f(acc2[c][r]);
            }

        // ---- stage h1, e1 = h1@Wq1b ----
#pragma unroll
        for (int c = 0; c < 4; ++c)
#pragma unroll
            for (int r = 0; r < 4; ++r)
                stg[(q * 4 + r) * 76 + (row + 16 * c)] = pack_split(acc1[c][r]);
        f32x4 eacc1[4];
#pragma unroll
        for (int c = 0; c < 4; ++c) eacc1[c] = (f32x4){0.f, 0.f, 0.f, 0.f};
#pragma unroll
        for (int kh = 0; kh < 2; ++kh) {
            bf16x8 ahi, alo;
            load_afrag(rowPtr, kh, q, &ahi, &alo);
            mm3(B1bH, B1bL, ahi, alo, eacc1, kh, l);
        }

        // ---- stage h2, e2 = h2@Wq2b ----
#pragma unroll
        for (int c = 0; c < 4; ++c)
#pragma unroll
            for (int r = 0; r < 4; ++r)
                stg[(q * 4 + r) * 76 + (row + 16 * c)] = pack_split(acc2[c][r]);
        f32x4 eacc2[4];
#pragma unroll
        for (int c = 0; c < 4; ++c) eacc2[c] = (f32x4){0.f, 0.f, 0.f, 0.f};
#pragma unroll
        for (int kh = 0; kh < 2; ++kh) {
            bf16x8 ahi, alo;
            load_afrag(rowPtr, kh, q, &ahi, &alo);
            mm3(B2bH, B2bL, ahi, alo, eacc2, kh, l);
        }

        // ---- equivariant scatter ----
#pragma unroll
        for (int r = 0; r < 4; ++r) {
            const int eo = q * 4 + r;
            const int vs = __shfl(evA, eo);
            const int vd = __shfl(evA, 16 + eo);
            const float d0 = __shfl(dvA, eo * 3 + 0);
            const float d1 = __shfl(dvA, eo * 3 + 1);
            const float d2 = __shfl(dvA, eo * 3 + 2);
            const float* fd = forceN + (size_t)vd * 3 * FDIM;
            float* fa = forceAcc + (size_t)vs * 3 * FDIM;
#pragma unroll
            for (int c = 0; c < 4; ++c) {
                const int n = row + 16 * c;
                const float a = eacc1[c][r];
                const float b = eacc2[c][r];
                atomicAdd(&fa[0 * FDIM + n], a * d0 + b * fd[0 * FDIM + n]);
                atomicAdd(&fa[1 * FDIM + n], a * d1 + b * fd[1 * FDIM + n]);
                atomicAdd(&fa[2 * FDIM + n], a * d2 + b * fd[2 * FDIM + n]);
            }
        }

        // ---- rotate ----
        evA = evB;
        dvA = dvB;
        daA = daB;
        dbA = dbB;
        grp = grpN;
    }
}

// ---------------- Kernel C: finalize nodes ----------------
__global__ __launch_bounds__(256) void node_final_kernel(
    const float* __restrict__ Wu, const float* __restrict__ gamma, const float* __restrict__ beta,
    float* __restrict__ atomAcc, const float* __restrict__ forceOut)
{
    __shared__ float Wus[FDIM][FDIM];
    const int f = threadIdx.x, ty = threadIdx.y;
    const int tid = ty * 64 + f;
    for (int i = tid; i < FDIM * FDIM; i += 256) ((float*)Wus)[i] = Wu[i];
    __syncthreads();
    const float gg = gamma[f], bb = beta[f];
    const int nw = gridDim.x * 4;
    for (int n = blockIdx.x * 4 + ty; n < N_NODES; n += nw) {
        const float f0 = forceOut[((size_t)n * 3 + 0) * FDIM + f];
        const float f1 = forceOut[((size_t)n * 3 + 1) * FDIM + f];
        const float f2 = forceOut[((size_t)n * 3 + 2) * FDIM + f];
        float r0 = 0.0f, r1 = 0.0f, r2 = 0.0f;
#pragma unroll 8
        for (int g = 0; g < FDIM; ++g) {
            const float w = Wus[g][f];
            r0 += bcast_lane(f0, g) * w;
            r1 += bcast_lane(f1, g) * w;
            r2 += bcast_lane(f2, g) * w;
        }
        float a = atomAcc[n * FDIM + f] + (f0 * r0 + f1 * r1 + f2 * r2);
        float s = a;
#pragma unroll
        for (int off = 32; off >= 1; off >>= 1) s += __shfl_xor(s, off, 64);
        const float mu = s * (1.0f / 64.0f);
        const float d = a - mu;
        float v = d * d;
#pragma unroll
        for (int off = 32; off >= 1; off >>= 1) v += __shfl_xor(v, off, 64);
        v *= (1.0f / 64.0f);
        atomAcc[n * FDIM + f] = d * rsqrtf(v + LN_EPS) * gg + bb;
    }
}

extern "C" void kernel_launch(void* const* d_in, const int* in_sizes, int n_in,
                              void* d_out, int out_size, void* d_ws, size_t ws_size,
                              hipStream_t stream)
{
    const float* atom_node  = (const float*)d_in[0];
    const float* force_node = (const float*)d_in[1];
    const float* dir_edge   = (const float*)d_in[2];
    const float* dist_edge  = (const float*)d_in[3];
    const int*   edge_index = (const int*)d_in[4];
    const float* W1   = (const float*)d_in[5];
    const float* b1   = (const float*)d_in[6];
    const float* W2   = (const float*)d_in[7];
    const float* b2   = (const float*)d_in[8];
    const float* We   = (const float*)d_in[9];
    const float* Wq1a = (const float*)d_in[10];
    const float* Wq1b = (const float*)d_in[11];
    const float* Wq2a = (const float*)d_in[12];
    const float* Wq2b = (const float*)d_in[13];
    const float* Wu   = (const float*)d_in[14];
    const float* gamma = (const float*)d_in[15];
    const float* beta  = (const float*)d_in[16];

    float* atomOut  = (float*)d_out;
    float* forceOut = (float*)d_out + (size_t)N_NODES * FDIM;
    float* mn = (float*)d_ws;

    hipMemcpyAsync(atomOut, atom_node, (size_t)N_NODES * FDIM * sizeof(float),
                   hipMemcpyDeviceToDevice, stream);
    hipMemcpyAsync(forceOut, force_node, (size_t)N_NODES * 3 * FDIM * sizeof(float),
                   hipMemcpyDeviceToDevice, stream);

    dim3 blk4(64, 4);
    dim3 blk16(64, 16);
    node_mlp_kernel<<<512, blk4, 0, stream>>>(atom_node, W1, b1, W2, b2, mn);
    edge_kernel<<<256, blk16, 0, stream>>>(dist_edge, dir_edge, edge_index, mn, We,
                                           Wq1a, Wq1b, Wq2a, Wq2b, force_node,
                                           atomOut, forceOut);
    node_final_kernel<<<512, blk4, 0, stream>>>(Wu, gamma, beta, atomOut, forceOut);
}

// Round 12
// 593.857 us; speedup vs baseline: 1.0387x; 1.0027x over previous
//
#include <hip/hip_runtime.h>

#define N_NODES 20000
#define N_EDGES 640000
#define FDIM 64
#define NB 20
#define LN_EPS 1e-5f
#define NW 12            // waves per block in edge kernel

typedef __attribute__((ext_vector_type(8))) short bf16x8;
typedef __attribute__((ext_vector_type(4))) float f32x4;

#define SEL_HI 0x07060302u
#define SEL_LO 0x05040100u
#define MFMA16 __builtin_amdgcn_mfma_f32_16x16x32_bf16

__device__ __forceinline__ float silu_f(float x) { return x / (1.0f + __expf(-x)); }

__device__ __forceinline__ float bcast_lane(float v, int lane) {
    return __int_as_float(__builtin_amdgcn_readlane(__float_as_int(v), lane));
}

__device__ __forceinline__ unsigned bf16_rn(float x) {
    unsigned u = __float_as_uint(x);
    return (u + 0x7FFFu + ((u >> 16) & 1u)) >> 16;
}

__device__ __forceinline__ unsigned pack_split(float x) {
    unsigned h = bf16_rn(x);
    unsigned lo = bf16_rn(x - __uint_as_float(h << 16));
    return (h << 16) | lo;
}

__device__ __forceinline__ void load_afrag(const unsigned* rowPtr, int kh, int q,
                                           bf16x8* ahi, bf16x8* alo) {
    const uint4 ra = *(const uint4*)(rowPtr + kh * 32 + q * 8);
    const uint4 rb = *(const uint4*)(rowPtr + kh * 32 + q * 8 + 4);
    union { unsigned u[4]; bf16x8 v; } H, L;
    H.u[0] = __builtin_amdgcn_perm(ra.y, ra.x, SEL_HI);
    H.u[1] = __builtin_amdgcn_perm(ra.w, ra.z, SEL_HI);
    H.u[2] = __builtin_amdgcn_perm(rb.y, rb.x, SEL_HI);
    H.u[3] = __builtin_amdgcn_perm(rb.w, rb.z, SEL_HI);
    L.u[0] = __builtin_amdgcn_perm(ra.y, ra.x, SEL_LO);
    L.u[1] = __builtin_amdgcn_perm(ra.w, ra.z, SEL_LO);
    L.u[2] = __builtin_amdgcn_perm(rb.y, rb.x, SEL_LO);
    L.u[3] = __builtin_amdgcn_perm(rb.w, rb.z, SEL_LO);
    *ahi = H.v;
    *alo = L.v;
}

__device__ __forceinline__ void mm3(const unsigned* Bhi, const unsigned* Blo,
                                    bf16x8 ahi, bf16x8 alo, f32x4* acc, int kh, int l) {
#pragma unroll
    for (int c = 0; c < 4; ++c) {
        bf16x8 bh = *(const bf16x8*)(Bhi + (kh * 4 + c) * 256 + l * 4);
        bf16x8 bl = *(const bf16x8*)(Blo + (kh * 4 + c) * 256 + l * 4);
        acc[c] = MFMA16(ahi, bh, acc[c], 0, 0, 0);
        acc[c] = MFMA16(ahi, bl, acc[c], 0, 0, 0);
        acc[c] = MFMA16(alo, bh, acc[c], 0, 0, 0);
    }
}

// ---------------- Kernel A: node MLP ----------------
__global__ __launch_bounds__(256) void node_mlp_kernel(
    const float* __restrict__ atom, const float* __restrict__ W1, const float* __restrict__ b1,
    const float* __restrict__ W2, const float* __restrict__ b2, float* __restrict__ mn)
{
    __shared__ float W1s[FDIM][FDIM];
    __shared__ float W2s[FDIM][FDIM];
    const int f = threadIdx.x, ty = threadIdx.y;
    const int tid = ty * 64 + f;
    for (int i = tid; i < FDIM * FDIM; i += 256) {
        ((float*)W1s)[i] = W1[i];
        ((float*)W2s)[i] = W2[i];
    }
    __syncthreads();
    const float bb1 = b1[f], bb2 = b2[f];
    const int nw = gridDim.x * 4;
    for (int n = blockIdx.x * 4 + ty; n < N_NODES; n += nw) {
        const float a = atom[n * FDIM + f];
        float h = bb1;
        for (int g = 0; g < FDIM; ++g) h += bcast_lane(a, g) * W1s[g][f];
        h = silu_f(h);
        float o = bb2;
        for (int g = 0; g < FDIM; ++g) o += bcast_lane(h, g) * W2s[g][f];
        mn[n * FDIM + f] = o;
    }
}

// ---------------- Kernel B: per-edge MFMA pipeline, 12 waves, drain-free ordering ----------------
// 768-thread blocks: 3 waves/SIMD co-residency -> ~170 reg/wave budget, so the small batch
// arrays (p[16], per-r fd[12]) live in real registers (1024-thread blocks capped us at ~64
// arch VGPRs and silently spilled them). Ordering rule everywhere: a VMEM load is never
// issued after an atomic whose drain would block the load's consumer:
//   - msg phase pass A: 32 mn gathers -> p[j] products, ZERO atomics interleaved
//   - msg phase pass B: me from LDS (lgkmcnt, not vmcnt) + 16 atomics, ZERO loads
//   - force scatter: per r-block, 12 fd loads, one wait, then 12 atomics
__global__ __launch_bounds__(64 * NW) void edge_kernel(
    const float* __restrict__ dist,   // [E,20]
    const float* __restrict__ dir,    // [E,3]
    const int* __restrict__ eidx,     // [2,E] int32
    const float* __restrict__ mn,     // [N,F]
    const float* __restrict__ We,     // [20,F]
    const float* __restrict__ Wq1a, const float* __restrict__ Wq1b,
    const float* __restrict__ Wq2a, const float* __restrict__ Wq2b,
    const float* __restrict__ forceN, // [N,3,F]
    float* __restrict__ atomAcc,      // [N,F]
    float* __restrict__ forceAcc)     // [N,3,F]
{
    __shared__ __align__(16) unsigned Bfr[16384];          // 64 KB weight frags
    __shared__ __align__(16) unsigned WeFr[2048];          // 8 KB We frags
    __shared__ __align__(16) unsigned Astg[NW][16][76];    // per-wave staging (~57 KB)

    const int l = threadIdx.x;
    const int ty = threadIdx.y;          // wave 0..NW-1
    const int q = l >> 4, row = l & 15;

    for (int t = ty; t < 32; t += NW) {
        const int mm = t >> 3, kh = (t >> 2) & 1, c = t & 3;
        const float* W = (mm == 0) ? Wq1a : (mm == 1) ? Wq2a : (mm == 2) ? Wq1b : Wq2b;
        const int n = c * 16 + row;
        const int kb = kh * 32 + q * 8;
        unsigned* hiP = &Bfr[(((mm * 2 + 0) * 2 + kh) * 4 + c) * 256 + l * 4];
        unsigned* loP = &Bfr[(((mm * 2 + 1) * 2 + kh) * 4 + c) * 256 + l * 4];
#pragma unroll
        for (int i = 0; i < 4; ++i) {
            float w0 = W[(kb + 2 * i) * FDIM + n];
            float w1 = W[(kb + 2 * i + 1) * FDIM + n];
            unsigned h0 = bf16_rn(w0);
            unsigned l0 = bf16_rn(w0 - __uint_as_float(h0 << 16));
            unsigned h1 = bf16_rn(w1);
            unsigned l1 = bf16_rn(w1 - __uint_as_float(h1 << 16));
            hiP[i] = h0 | (h1 << 16);
            loP[i] = l0 | (l1 << 16);
        }
    }
    for (int c = ty; c < 4; c += NW) {
        const int n = c * 16 + row;
        unsigned* hiP = &WeFr[(0 * 4 + c) * 256 + l * 4];
        unsigned* loP = &WeFr[(1 * 4 + c) * 256 + l * 4];
#pragma unroll
        for (int i = 0; i < 4; ++i) {
            const int k0 = q * 8 + 2 * i, k1 = k0 + 1;
            float w0 = (k0 < NB) ? We[k0 * FDIM + n] : 0.0f;
            float w1 = (k1 < NB) ? We[k1 * FDIM + n] : 0.0f;
            unsigned h0 = bf16_rn(w0);
            unsigned l0 = bf16_rn(w0 - __uint_as_float(h0 << 16));
            unsigned h1 = bf16_rn(w1);
            unsigned l1 = bf16_rn(w1 - __uint_as_float(h1 << 16));
            hiP[i] = h0 | (h1 << 16);
            loP[i] = l0 | (l1 << 16);
        }
    }
    __syncthreads();

    const unsigned* B1aH = Bfr + 0 * 2048; const unsigned* B1aL = Bfr + 1 * 2048;
    const unsigned* B2aH = Bfr + 2 * 2048; const unsigned* B2aL = Bfr + 3 * 2048;
    const unsigned* B1bH = Bfr + 4 * 2048; const unsigned* B1bL = Bfr + 5 * 2048;
    const unsigned* B2bH = Bfr + 6 * 2048; const unsigned* B2bL = Bfr + 7 * 2048;
    const unsigned* WeH = WeFr;            const unsigned* WeL = WeFr + 1024;

    unsigned* stg = &Astg[ty][0][0];
    const unsigned* rowPtr = &Astg[ty][row][0];

    const int ngroups = N_EDGES / 16;
    const int stride = gridDim.x * NW;
    for (int grp = blockIdx.x * NW + ty; grp < ngroups; grp += stride) {
        const int e0 = grp * 16;

        // ---- group metadata ----
        int ev = 0;
        if (l < 32) ev = eidx[(l < 16) ? (e0 + l) : (N_EDGES + e0 + (l - 16))];
        float dv = (l < 48) ? dir[e0 * 3 + l] : 0.0f;

        // ---- me = dist16x20 @ We20x64 via MFMA ----
        const float* dp = dist + (size_t)(e0 + row) * NB + q * 8;
        float4 da = {0.f, 0.f, 0.f, 0.f}, db = {0.f, 0.f, 0.f, 0.f};
        if (q < 2)       { da = *(const float4*)dp; db = *(const float4*)(dp + 4); }
        else if (q == 2) { da = *(const float4*)dp; }
        unsigned s0 = pack_split(da.x), s1 = pack_split(da.y);
        unsigned s2 = pack_split(da.z), s3 = pack_split(da.w);
        unsigned s4 = pack_split(db.x), s5 = pack_split(db.y);
        unsigned s6 = pack_split(db.z), s7 = pack_split(db.w);
        union { unsigned u[4]; bf16x8 v; } AH, AL;
        AH.u[0] = __builtin_amdgcn_perm(s1, s0, SEL_HI);
        AH.u[1] = __builtin_amdgcn_perm(s3, s2, SEL_HI);
        AH.u[2] = __builtin_amdgcn_perm(s5, s4, SEL_HI);
        AH.u[3] = __builtin_amdgcn_perm(s7, s6, SEL_HI);
        AL.u[0] = __builtin_amdgcn_perm(s1, s0, SEL_LO);
        AL.u[1] = __builtin_amdgcn_perm(s3, s2, SEL_LO);
        AL.u[2] = __builtin_amdgcn_perm(s5, s4, SEL_LO);
        AL.u[3] = __builtin_amdgcn_perm(s7, s6, SEL_LO);

        f32x4 me4[4];
#pragma unroll
        for (int c = 0; c < 4; ++c) me4[c] = (f32x4){0.f, 0.f, 0.f, 0.f};
        mm3(WeH, WeL, AH.v, AL.v, me4, 0, l);
#pragma unroll
        for (int c = 0; c < 4; ++c)
#pragma unroll
            for (int r = 0; r < 4; ++r)
                stg[(q * 4 + r) * 76 + (row + 16 * c)] = __float_as_uint(me4[c][r]);

        // ---- msg pass A: all 32 mn gathers -> 16 products, NO atomics ----
        float p[16];
#pragma unroll
        for (int j = 0; j < 16; ++j) {
            const int src = __builtin_amdgcn_readlane(ev, j);
            const int dst = __builtin_amdgcn_readlane(ev, 16 + j);
            p[j] = mn[(size_t)src * FDIM + l] * mn[(size_t)dst * FDIM + l];
        }
        // ---- msg pass B: LDS reads + 16 atomics, NO VMEM loads ----
#pragma unroll
        for (int j = 0; j < 16; ++j) {
            const int src = __builtin_amdgcn_readlane(ev, j);
            const float m = __uint_as_float(stg[j * 76 + l]) * p[j];
            atomicAdd(&atomAcc[(size_t)src * FDIM + l], m);
            stg[j * 76 + l] = pack_split(m);
        }

        // ---- h-phase: h1 = msg@Wq1a, h2 = msg@Wq2a ----
        f32x4 acc1[4], acc2[4];
#pragma unroll
        for (int c = 0; c < 4; ++c) {
            acc1[c] = (f32x4){0.f, 0.f, 0.f, 0.f};
            acc2[c] = (f32x4){0.f, 0.f, 0.f, 0.f};
        }
#pragma unroll
        for (int kh = 0; kh < 2; ++kh) {
            bf16x8 ahi, alo;
            load_afrag(rowPtr, kh, q, &ahi, &alo);
            mm3(B1aH, B1aL, ahi, alo, acc1, kh, l);
            mm3(B2aH, B2aL, ahi, alo, acc2, kh, l);
        }
#pragma unroll
        for (int c = 0; c < 4; ++c)
#pragma unroll
            for (int r = 0; r < 4; ++r) {
                acc1[c][r] = silu_f(acc1[c][r]);
                acc2[c][r] = silu_f(acc2[c][r]);
            }

        // ---- stage h1, e1 = h1@Wq1b ----
#pragma unroll
        for (int c = 0; c < 4; ++c)
#pragma unroll
            for (int r = 0; r < 4; ++r)
                stg[(q * 4 + r) * 76 + (row + 16 * c)] = pack_split(acc1[c][r]);
        f32x4 eacc1[4];
#pragma unroll
        for (int c = 0; c < 4; ++c) eacc1[c] = (f32x4){0.f, 0.f, 0.f, 0.f};
#pragma unroll
        for (int kh = 0; kh < 2; ++kh) {
            bf16x8 ahi, alo;
            load_afrag(rowPtr, kh, q, &ahi, &alo);
            mm3(B1bH, B1bL, ahi, alo, eacc1, kh, l);
        }

        // ---- stage h2, e2 = h2@Wq2b ----
#pragma unroll
        for (int c = 0; c < 4; ++c)
#pragma unroll
            for (int r = 0; r < 4; ++r)
                stg[(q * 4 + r) * 76 + (row + 16 * c)] = pack_split(acc2[c][r]);
        f32x4 eacc2[4];
#pragma unroll
        for (int c = 0; c < 4; ++c) eacc2[c] = (f32x4){0.f, 0.f, 0.f, 0.f};
#pragma unroll
        for (int kh = 0; kh < 2; ++kh) {
            bf16x8 ahi, alo;
            load_afrag(rowPtr, kh, q, &ahi, &alo);
            mm3(B2bH, B2bL, ahi, alo, eacc2, kh, l);
        }

        // ---- equivariant scatter: per r-block, batch 12 fd loads THEN 12 atomics ----
#pragma unroll
        for (int r = 0; r < 4; ++r) {
            const int eo = q * 4 + r;
            const int vs = __shfl(ev, eo);
            const int vd = __shfl(ev, 16 + eo);
            const float d0 = __shfl(dv, eo * 3 + 0);
            const float d1 = __shfl(dv, eo * 3 + 1);
            const float d2 = __shfl(dv, eo * 3 + 2);
            const float* fd = forceN + (size_t)vd * 3 * FDIM;
            float f0[4], f1[4], f2[4];
#pragma unroll
            for (int c = 0; c < 4; ++c) {
                const int n = row + 16 * c;
                f0[c] = fd[0 * FDIM + n];
                f1[c] = fd[1 * FDIM + n];
                f2[c] = fd[2 * FDIM + n];
            }
            float* fa = forceAcc + (size_t)vs * 3 * FDIM;
#pragma unroll
            for (int c = 0; c < 4; ++c) {
                const int n = row + 16 * c;
                atomicAdd(&fa[0 * FDIM + n], eacc1[c][r] * d0 + eacc2[c][r] * f0[c]);
                atomicAdd(&fa[1 * FDIM + n], eacc1[c][r] * d1 + eacc2[c][r] * f1[c]);
                atomicAdd(&fa[2 * FDIM + n], eacc1[c][r] * d2 + eacc2[c][r] * f2[c]);
            }
        }
    }
}

// ---------------- Kernel C: finalize nodes ----------------
__global__ __launch_bounds__(256) void node_final_kernel(
    const float* __restrict__ Wu, const float* __restrict__ gamma, const float* __restrict__ beta,
    float* __restrict__ atomAcc, const float* __restrict__ forceOut)
{
    __shared__ float Wus[FDIM][FDIM];
    const int f = threadIdx.x, ty = threadIdx.y;
    const int tid = ty * 64 + f;
    for (int i = tid; i < FDIM * FDIM; i += 256) ((float*)Wus)[i] = Wu[i];
    __syncthreads();
    const float gg = gamma[f], bb = beta[f];
    const int nw = gridDim.x * 4;
    for (int n = blockIdx.x * 4 + ty; n < N_NODES; n += nw) {
        const float f0 = forceOut[((size_t)n * 3 + 0) * FDIM + f];
        const float f1 = forceOut[((size_t)n * 3 + 1) * FDIM + f];
        const float f2 = forceOut[((size_t)n * 3 + 2) * FDIM + f];
        float r0 = 0.0f, r1 = 0.0f, r2 = 0.0f;
#pragma unroll 8
        for (int g = 0; g < FDIM; ++g) {
            const float w = Wus[g][f];
            r0 += bcast_lane(f0, g) * w;
            r1 += bcast_lane(f1, g) * w;
            r2 += bcast_lane(f2, g) * w;
        }
        float a = atomAcc[n * FDIM + f] + (f0 * r0 + f1 * r1 + f2 * r2);
        float s = a;
#pragma unroll
        for (int off = 32; off >= 1; off >>= 1) s += __shfl_xor(s, off, 64);
        const float mu = s * (1.0f / 64.0f);
        const float d = a - mu;
        float v = d * d;
#pragma unroll
        for (int off = 32; off >= 1; off >>= 1) v += __shfl_xor(v, off, 64);
        v *= (1.0f / 64.0f);
        atomAcc[n * FDIM + f] = d * rsqrtf(v + LN_EPS) * gg + bb;
    }
}

extern "C" void kernel_launch(void* const* d_in, const int* in_sizes, int n_in,
                              void* d_out, int out_size, void* d_ws, size_t ws_size,
                              hipStream_t stream)
{
    const float* atom_node  = (const float*)d_in[0];
    const float* force_node = (const float*)d_in[1];
    const float* dir_edge   = (const float*)d_in[2];
    const float* dist_edge  = (const float*)d_in[3];
    const int*   edge_index = (const int*)d_in[4];
    const float* W1   = (const float*)d_in[5];
    const float* b1   = (const float*)d_in[6];
    const float* W2   = (const float*)d_in[7];
    const float* b2   = (const float*)d_in[8];
    const float* We   = (const float*)d_in[9];
    const float* Wq1a = (const float*)d_in[10];
    const float* Wq1b = (const float*)d_in[11];
    const float* Wq2a = (const float*)d_in[12];
    const float* Wq2b = (const float*)d_in[13];
    const float* Wu   = (const float*)d_in[14];
    const float* gamma = (const float*)d_in[15];
    const float* beta  = (const float*)d_in[16];

    float* atomOut  = (float*)d_out;
    float* forceOut = (float*)d_out + (size_t)N_NODES * FDIM;
    float* mn = (float*)d_ws;

    hipMemcpyAsync(atomOut, atom_node, (size_t)N_NODES * FDIM * sizeof(float),
                   hipMemcpyDeviceToDevice, stream);
    hipMemcpyAsync(forceOut, force_node, (size_t)N_NODES * 3 * FDIM * sizeof(float),
                   hipMemcpyDeviceToDevice, stream);

    dim3 blk4(64, 4);
    dim3 blkE(64, NW);
    node_mlp_kernel<<<512, blk4, 0, stream>>>(atom_node, W1, b1, W2, b2, mn);
    edge_kernel<<<256, blkE, 0, stream>>>(dist_edge, dir_edge, edge_index, mn, We,
                                          Wq1a, Wq1b, Wq2a, Wq2b, force_node,
                                          atomOut, forceOut);
    node_final_kernel<<<512, blk4, 0, stream>>>(Wu, gamma, beta, atomOut, forceOut);
}

// Round 13
// 590.080 us; speedup vs baseline: 1.0454x; 1.0064x over previous
//
#include <hip/hip_runtime.h>

#define N_NODES 20000
#define N_EDGES 640000
#define FDIM 64
#define NB 20
#define LN_EPS 1e-5f
#define NW 8             // waves per block in edge kernel (512 thr -> 2 waves/SIMD -> 256-reg budget)

typedef __attribute__((ext_vector_type(8))) short bf16x8;
typedef __attribute__((ext_vector_type(4))) float f32x4;

#define SEL_HI 0x07060302u
#define SEL_LO 0x05040100u
#define MFMA16 __builtin_amdgcn_mfma_f32_16x16x32_bf16

__device__ __forceinline__ float silu_f(float x) { return x / (1.0f + __expf(-x)); }

__device__ __forceinline__ float bcast_lane(float v, int lane) {
    return __int_as_float(__builtin_amdgcn_readlane(__float_as_int(v), lane));
}

__device__ __forceinline__ unsigned bf16_rn(float x) {
    unsigned u = __float_as_uint(x);
    return (u + 0x7FFFu + ((u >> 16) & 1u)) >> 16;
}

__device__ __forceinline__ unsigned pack_split(float x) {
    unsigned h = bf16_rn(x);
    unsigned lo = bf16_rn(x - __uint_as_float(h << 16));
    return (h << 16) | lo;
}

__device__ __forceinline__ void load_afrag(const unsigned* rowPtr, int kh, int q,
                                           bf16x8* ahi, bf16x8* alo) {
    const uint4 ra = *(const uint4*)(rowPtr + kh * 32 + q * 8);
    const uint4 rb = *(const uint4*)(rowPtr + kh * 32 + q * 8 + 4);
    union { unsigned u[4]; bf16x8 v; } H, L;
    H.u[0] = __builtin_amdgcn_perm(ra.y, ra.x, SEL_HI);
    H.u[1] = __builtin_amdgcn_perm(ra.w, ra.z, SEL_HI);
    H.u[2] = __builtin_amdgcn_perm(rb.y, rb.x, SEL_HI);
    H.u[3] = __builtin_amdgcn_perm(rb.w, rb.z, SEL_HI);
    L.u[0] = __builtin_amdgcn_perm(ra.y, ra.x, SEL_LO);
    L.u[1] = __builtin_amdgcn_perm(ra.w, ra.z, SEL_LO);
    L.u[2] = __builtin_amdgcn_perm(rb.y, rb.x, SEL_LO);
    L.u[3] = __builtin_amdgcn_perm(rb.w, rb.z, SEL_LO);
    *ahi = H.v;
    *alo = L.v;
}

__device__ __forceinline__ void mm3(const unsigned* Bhi, const unsigned* Blo,
                                    bf16x8 ahi, bf16x8 alo, f32x4* acc, int kh, int l) {
#pragma unroll
    for (int c = 0; c < 4; ++c) {
        bf16x8 bh = *(const bf16x8*)(Bhi + (kh * 4 + c) * 256 + l * 4);
        bf16x8 bl = *(const bf16x8*)(Blo + (kh * 4 + c) * 256 + l * 4);
        acc[c] = MFMA16(ahi, bh, acc[c], 0, 0, 0);
        acc[c] = MFMA16(ahi, bl, acc[c], 0, 0, 0);
        acc[c] = MFMA16(alo, bh, acc[c], 0, 0, 0);
    }
}

// ---------------- Kernel A: node MLP ----------------
__global__ __launch_bounds__(256) void node_mlp_kernel(
    const float* __restrict__ atom, const float* __restrict__ W1, const float* __restrict__ b1,
    const float* __restrict__ W2, const float* __restrict__ b2, float* __restrict__ mn)
{
    __shared__ float W1s[FDIM][FDIM];
    __shared__ float W2s[FDIM][FDIM];
    const int f = threadIdx.x, ty = threadIdx.y;
    const int tid = ty * 64 + f;
    for (int i = tid; i < FDIM * FDIM; i += 256) {
        ((float*)W1s)[i] = W1[i];
        ((float*)W2s)[i] = W2[i];
    }
    __syncthreads();
    const float bb1 = b1[f], bb2 = b2[f];
    const int nw = gridDim.x * 4;
    for (int n = blockIdx.x * 4 + ty; n < N_NODES; n += nw) {
        const float a = atom[n * FDIM + f];
        float h = bb1;
        for (int g = 0; g < FDIM; ++g) h += bcast_lane(a, g) * W1s[g][f];
        h = silu_f(h);
        float o = bb2;
        for (int g = 0; g < FDIM; ++g) o += bcast_lane(h, g) * W2s[g][f];
        mn[n * FDIM + f] = o;
    }
}

// ---------------- Kernel B: per-edge MFMA pipeline, 8 waves, true register pipelining ----------------
// 512-thread blocks + __launch_bounds__(512,2): 2 waves/SIMD co-residency -> 256-VGPR budget,
// so the cross-group prefetch state (ev/dir/dist/mn[32]) genuinely lives in registers
// (at 1024 thr the 64-VGPR cap silently spilled it; at 768 thr there was no room for prefetch).
// Ordering: msg pass A (loads only) / pass B (LDS+atomics only); scatter batches loads before atomics.
__global__ __launch_bounds__(64 * NW, 2) void edge_kernel(
    const float* __restrict__ dist,   // [E,20]
    const float* __restrict__ dir,    // [E,3]
    const int* __restrict__ eidx,     // [2,E] int32
    const float* __restrict__ mn,     // [N,F]
    const float* __restrict__ We,     // [20,F]
    const float* __restrict__ Wq1a, const float* __restrict__ Wq1b,
    const float* __restrict__ Wq2a, const float* __restrict__ Wq2b,
    const float* __restrict__ forceN, // [N,3,F]
    float* __restrict__ atomAcc,      // [N,F]
    float* __restrict__ forceAcc)     // [N,3,F]
{
    __shared__ __align__(16) unsigned Bfr[16384];          // 64 KB weight frags
    __shared__ __align__(16) unsigned WeFr[2048];          // 8 KB We frags
    __shared__ __align__(16) unsigned Astg[NW][16][76];    // per-wave staging (~38 KB)

    const int l = threadIdx.x;
    const int ty = threadIdx.y;          // wave 0..NW-1
    const int q = l >> 4, row = l & 15;

    for (int t = ty; t < 32; t += NW) {
        const int mm = t >> 3, kh = (t >> 2) & 1, c = t & 3;
        const float* W = (mm == 0) ? Wq1a : (mm == 1) ? Wq2a : (mm == 2) ? Wq1b : Wq2b;
        const int n = c * 16 + row;
        const int kb = kh * 32 + q * 8;
        unsigned* hiP = &Bfr[(((mm * 2 + 0) * 2 + kh) * 4 + c) * 256 + l * 4];
        unsigned* loP = &Bfr[(((mm * 2 + 1) * 2 + kh) * 4 + c) * 256 + l * 4];
#pragma unroll
        for (int i = 0; i < 4; ++i) {
            float w0 = W[(kb + 2 * i) * FDIM + n];
            float w1 = W[(kb + 2 * i + 1) * FDIM + n];
            unsigned h0 = bf16_rn(w0);
            unsigned l0 = bf16_rn(w0 - __uint_as_float(h0 << 16));
            unsigned h1 = bf16_rn(w1);
            unsigned l1 = bf16_rn(w1 - __uint_as_float(h1 << 16));
            hiP[i] = h0 | (h1 << 16);
            loP[i] = l0 | (l1 << 16);
        }
    }
    for (int c = ty; c < 4; c += NW) {
        const int n = c * 16 + row;
        unsigned* hiP = &WeFr[(0 * 4 + c) * 256 + l * 4];
        unsigned* loP = &WeFr[(1 * 4 + c) * 256 + l * 4];
#pragma unroll
        for (int i = 0; i < 4; ++i) {
            const int k0 = q * 8 + 2 * i, k1 = k0 + 1;
            float w0 = (k0 < NB) ? We[k0 * FDIM + n] : 0.0f;
            float w1 = (k1 < NB) ? We[k1 * FDIM + n] : 0.0f;
            unsigned h0 = bf16_rn(w0);
            unsigned l0 = bf16_rn(w0 - __uint_as_float(h0 << 16));
            unsigned h1 = bf16_rn(w1);
            unsigned l1 = bf16_rn(w1 - __uint_as_float(h1 << 16));
            hiP[i] = h0 | (h1 << 16);
            loP[i] = l0 | (l1 << 16);
        }
    }
    __syncthreads();

    const unsigned* B1aH = Bfr + 0 * 2048; const unsigned* B1aL = Bfr + 1 * 2048;
    const unsigned* B2aH = Bfr + 2 * 2048; const unsigned* B2aL = Bfr + 3 * 2048;
    const unsigned* B1bH = Bfr + 4 * 2048; const unsigned* B1bL = Bfr + 5 * 2048;
    const unsigned* B2bH = Bfr + 6 * 2048; const unsigned* B2bL = Bfr + 7 * 2048;
    const unsigned* WeH = WeFr;            const unsigned* WeL = WeFr + 1024;

    unsigned* stg = &Astg[ty][0][0];
    const unsigned* rowPtr = &Astg[ty][row][0];

    const int ngroups = N_EDGES / 16;
    const int stride = gridDim.x * NW;
    int grp = blockIdx.x * NW + ty;

    // ---- prologue: group 'grp' metadata + mn products in registers ----
    int e0 = grp * 16;
    int evA = (l < 32) ? eidx[(l < 16) ? (e0 + l) : (N_EDGES + e0 + (l - 16))] : 0;
    float dvA = (l < 48) ? dir[e0 * 3 + l] : 0.0f;
    float4 daA = {0.f, 0.f, 0.f, 0.f}, dbA = {0.f, 0.f, 0.f, 0.f};
    {
        const float* dp = dist + (size_t)(e0 + row) * NB + q * 8;
        if (q < 2)       { daA = *(const float4*)dp; dbA = *(const float4*)(dp + 4); }
        else if (q == 2) { daA = *(const float4*)dp; }
    }
    float pA[16];
#pragma unroll
    for (int j = 0; j < 16; ++j) {
        const int src = __builtin_amdgcn_readlane(evA, j);
        const int dst = __builtin_amdgcn_readlane(evA, 16 + j);
        pA[j] = mn[(size_t)src * FDIM + l] * mn[(size_t)dst * FDIM + l];
    }

    while (grp < ngroups) {
        e0 = grp * 16;
        const int grpN = grp + stride;
        const int e0n = (grpN < ngroups) ? grpN * 16 : 0;

        // ---- issue next-group metadata + dist loads (fly under me-phase) ----
        const int evB = (l < 32) ? eidx[(l < 16) ? (e0n + l) : (N_EDGES + e0n + (l - 16))] : 0;
        const float dvB = (l < 48) ? dir[e0n * 3 + l] : 0.0f;
        float4 daB = {0.f, 0.f, 0.f, 0.f}, dbB = {0.f, 0.f, 0.f, 0.f};
        {
            const float* dpn = dist + (size_t)(e0n + row) * NB + q * 8;
            if (q < 2)       { daB = *(const float4*)dpn; dbB = *(const float4*)(dpn + 4); }
            else if (q == 2) { daB = *(const float4*)dpn; }
        }

        // ---- me = dist16x20 @ We20x64 via MFMA (prefetched dist) ----
        unsigned s0 = pack_split(daA.x), s1 = pack_split(daA.y);
        unsigned s2 = pack_split(daA.z), s3 = pack_split(daA.w);
        unsigned s4 = pack_split(dbA.x), s5 = pack_split(dbA.y);
        unsigned s6 = pack_split(dbA.z), s7 = pack_split(dbA.w);
        union { unsigned u[4]; bf16x8 v; } AH, AL;
        AH.u[0] = __builtin_amdgcn_perm(s1, s0, SEL_HI);
        AH.u[1] = __builtin_amdgcn_perm(s3, s2, SEL_HI);
        AH.u[2] = __builtin_amdgcn_perm(s5, s4, SEL_HI);
        AH.u[3] = __builtin_amdgcn_perm(s7, s6, SEL_HI);
        AL.u[0] = __builtin_amdgcn_perm(s1, s0, SEL_LO);
        AL.u[1] = __builtin_amdgcn_perm(s3, s2, SEL_LO);
        AL.u[2] = __builtin_amdgcn_perm(s5, s4, SEL_LO);
        AL.u[3] = __builtin_amdgcn_perm(s7, s6, SEL_LO);

        f32x4 me4[4];
#pragma unroll
        for (int c = 0; c < 4; ++c) me4[c] = (f32x4){0.f, 0.f, 0.f, 0.f};
        mm3(WeH, WeL, AH.v, AL.v, me4, 0, l);
#pragma unroll
        for (int c = 0; c < 4; ++c)
#pragma unroll
            for (int r = 0; r < 4; ++r)
                stg[(q * 4 + r) * 76 + (row + 16 * c)] = __float_as_uint(me4[c][r]);

        // ---- msg pass B: LDS me * prefetched products, 16 atomics, NO loads ----
#pragma unroll
        for (int j = 0; j < 16; ++j) {
            const int src = __builtin_amdgcn_readlane(evA, j);
            const float m = __uint_as_float(stg[j * 76 + l]) * pA[j];
            atomicAdd(&atomAcc[(size_t)src * FDIM + l], m);
            stg[j * 76 + l] = pack_split(m);
        }

        // ---- issue next-group mn gathers (fly under the three MFMA phases) ----
#pragma unroll
        for (int j = 0; j < 16; ++j) {
            const int srcN = __builtin_amdgcn_readlane(evB, j);
            const int dstN = __builtin_amdgcn_readlane(evB, 16 + j);
            pA[j] = mn[(size_t)srcN * FDIM + l] * mn[(size_t)dstN * FDIM + l];
        }

        // ---- h-phase: h1 = msg@Wq1a, h2 = msg@Wq2a ----
        f32x4 acc1[4], acc2[4];
#pragma unroll
        for (int c = 0; c < 4; ++c) {
            acc1[c] = (f32x4){0.f, 0.f, 0.f, 0.f};
            acc2[c] = (f32x4){0.f, 0.f, 0.f, 0.f};
        }
#pragma unroll
        for (int kh = 0; kh < 2; ++kh) {
            bf16x8 ahi, alo;
            load_afrag(rowPtr, kh, q, &ahi, &alo);
            mm3(B1aH, B1aL, ahi, alo, acc1, kh, l);
            mm3(B2aH, B2aL, ahi, alo, acc2, kh, l);
        }
#pragma unroll
        for (int c = 0; c < 4; ++c)
#pragma unroll
            for (int r = 0; r < 4; ++r) {
                acc1[c][r] = silu_f(acc1[c][r]);
                acc2[c][r] = silu_f(acc2[c][r]);
            }

        // ---- stage h1, e1 = h1@Wq1b ----
#pragma unroll
        for (int c = 0; c < 4; ++c)
#pragma unroll
            for (int r = 0; r < 4; ++r)
                stg[(q * 4 + r) * 76 + (row + 16 * c)] = pack_split(acc1[c][r]);
        f32x4 eacc1[4];
#pragma unroll
        for (int c = 0; c < 4; ++c) eacc1[c] = (f32x4){0.f, 0.f, 0.f, 0.f};
#pragma unroll
        for (int kh = 0; kh < 2; ++kh) {
            bf16x8 ahi, alo;
            load_afrag(rowPtr, kh, q, &ahi, &alo);
            mm3(B1bH, B1bL, ahi, alo, eacc1, kh, l);
        }

        // ---- stage h2, e2 = h2@Wq2b ----
#pragma unroll
        for (int c = 0; c < 4; ++c)
#pragma unroll
            for (int r = 0; r < 4; ++r)
                stg[(q * 4 + r) * 76 + (row + 16 * c)] = pack_split(acc2[c][r]);
        f32x4 eacc2[4];
#pragma unroll
        for (int c = 0; c < 4; ++c) eacc2[c] = (f32x4){0.f, 0.f, 0.f, 0.f};
#pragma unroll
        for (int kh = 0; kh < 2; ++kh) {
            bf16x8 ahi, alo;
            load_afrag(rowPtr, kh, q, &ahi, &alo);
            mm3(B2bH, B2bL, ahi, alo, eacc2, kh, l);
        }

        // ---- equivariant scatter: per r-block, batch 12 fd loads THEN 12 atomics ----
#pragma unroll
        for (int r = 0; r < 4; ++r) {
            const int eo = q * 4 + r;
            const int vs = __shfl(evA, eo);
            const int vd = __shfl(evA, 16 + eo);
            const float d0 = __shfl(dvA, eo * 3 + 0);
            const float d1 = __shfl(dvA, eo * 3 + 1);
            const float d2 = __shfl(dvA, eo * 3 + 2);
            const float* fd = forceN + (size_t)vd * 3 * FDIM;
            float f0[4], f1[4], f2[4];
#pragma unroll
            for (int c = 0; c < 4; ++c) {
                const int n = row + 16 * c;
                f0[c] = fd[0 * FDIM + n];
                f1[c] = fd[1 * FDIM + n];
                f2[c] = fd[2 * FDIM + n];
            }
            float* fa = forceAcc + (size_t)vs * 3 * FDIM;
#pragma unroll
            for (int c = 0; c < 4; ++c) {
                const int n = row + 16 * c;
                atomicAdd(&fa[0 * FDIM + n], eacc1[c][r] * d0 + eacc2[c][r] * f0[c]);
                atomicAdd(&fa[1 * FDIM + n], eacc1[c][r] * d1 + eacc2[c][r] * f1[c]);
                atomicAdd(&fa[2 * FDIM + n], eacc1[c][r] * d2 + eacc2[c][r] * f2[c]);
            }
        }

        // ---- rotate prefetched state ----
        evA = evB;
        dvA = dvB;
        daA = daB;
        dbA = dbB;
        grp = grpN;
    }
}

// ---------------- Kernel C: finalize nodes ----------------
__global__ __launch_bounds__(256) void node_final_kernel(
    const float* __restrict__ Wu, const float* __restrict__ gamma, const float* __restrict__ beta,
    float* __restrict__ atomAcc, const float* __restrict__ forceOut)
{
    __shared__ float Wus[FDIM][FDIM];
    const int f = threadIdx.x, ty = threadIdx.y;
    const int tid = ty * 64 + f;
    for (int i = tid; i < FDIM * FDIM; i += 256) ((float*)Wus)[i] = Wu[i];
    __syncthreads();
    const float gg = gamma[f], bb = beta[f];
    const int nw = gridDim.x * 4;
    for (int n = blockIdx.x * 4 + ty; n < N_NODES; n += nw) {
        const float f0 = forceOut[((size_t)n * 3 + 0) * FDIM + f];
        const float f1 = forceOut[((size_t)n * 3 + 1) * FDIM + f];
        const float f2 = forceOut[((size_t)n * 3 + 2) * FDIM + f];
        float r0 = 0.0f, r1 = 0.0f, r2 = 0.0f;
#pragma unroll 8
        for (int g = 0; g < FDIM; ++g) {
            const float w = Wus[g][f];
            r0 += bcast_lane(f0, g) * w;
            r1 += bcast_lane(f1, g) * w;
            r2 += bcast_lane(f2, g) * w;
        }
        float a = atomAcc[n * FDIM + f] + (f0 * r0 + f1 * r1 + f2 * r2);
        float s = a;
#pragma unroll
        for (int off = 32; off >= 1; off >>= 1) s += __shfl_xor(s, off, 64);
        const float mu = s * (1.0f / 64.0f);
        const float d = a - mu;
        float v = d * d;
#pragma unroll
        for (int off = 32; off >= 1; off >>= 1) v += __shfl_xor(v, off, 64);
        v *= (1.0f / 64.0f);
        atomAcc[n * FDIM + f] = d * rsqrtf(v + LN_EPS) * gg + bb;
    }
}

extern "C" void kernel_launch(void* const* d_in, const int* in_sizes, int n_in,
                              void* d_out, int out_size, void* d_ws, size_t ws_size,
                              hipStream_t stream)
{
    const float* atom_node  = (const float*)d_in[0];
    const float* force_node = (const float*)d_in[1];
    const float* dir_edge   = (const float*)d_in[2];
    const float* dist_edge  = (const float*)d_in[3];
    const int*   edge_index = (const int*)d_in[4];
    const float* W1   = (const float*)d_in[5];
    const float* b1   = (const float*)d_in[6];
    const float* W2   = (const float*)d_in[7];
    const float* b2   = (const float*)d_in[8];
    const float* We   = (const float*)d_in[9];
    const float* Wq1a = (const float*)d_in[10];
    const float* Wq1b = (const float*)d_in[11];
    const float* Wq2a = (const float*)d_in[12];
    const float* Wq2b = (const float*)d_in[13];
    const float* Wu   = (const float*)d_in[14];
    const float* gamma = (const float*)d_in[15];
    const float* beta  = (const float*)d_in[16];

    float* atomOut  = (float*)d_out;
    float* forceOut = (float*)d_out + (size_t)N_NODES * FDIM;
    float* mn = (float*)d_ws;

    hipMemcpyAsync(atomOut, atom_node, (size_t)N_NODES * FDIM * sizeof(float),
                   hipMemcpyDeviceToDevice, stream);
    hipMemcpyAsync(forceOut, force_node, (size_t)N_NODES * 3 * FDIM * sizeof(float),
                   hipMemcpyDeviceToDevice, stream);

    dim3 blk4(64, 4);
    dim3 blkE(64, NW);
    node_mlp_kernel<<<512, blk4, 0, stream>>>(atom_node, W1, b1, W2, b2, mn);
    edge_kernel<<<256, blkE, 0, stream>>>(dist_edge, dir_edge, edge_index, mn, We,
                                          Wq1a, Wq1b, Wq2a, Wq2b, force_node,
                                          atomOut, forceOut);
    node_final_kernel<<<512, blk4, 0, stream>>>(Wu, gamma, beta, atomOut, forceOut);
}